// Round 7
// baseline (156.689 us; speedup 1.0000x reference)
//
#include <hip/hip_runtime.h>

typedef _Float16 half_t;
typedef _Float16 h8 __attribute__((ext_vector_type(8)));
typedef _Float16 h4 __attribute__((ext_vector_type(4)));
typedef _Float16 h2 __attribute__((ext_vector_type(2)));
typedef float f32x4 __attribute__((ext_vector_type(4)));
typedef float f32x16 __attribute__((ext_vector_type(16)));

#define S_LEN 2048
#define DMODEL 1024
#define NHEAD 16
#define HDK 64
#define NB 2
#define MROWS (NB * S_LEN)  // 4096
#define LOG2E 1.44269504089f

// ---------------------------------------------------------------------------
__device__ __forceinline__ void gload_lds16(const void* g, void* l) {
  __builtin_amdgcn_global_load_lds(
      (const __attribute__((address_space(1))) unsigned int*)g,
      (__attribute__((address_space(3))) unsigned int*)l, 16, 0, 0);
}

// v_exp_f32 computes 2^x natively (scores carry log2e folded in from Q scale)
__device__ __forceinline__ float fast_exp2(float x) {
  float r;
  asm("v_exp_f32 %0, %1" : "=v"(r) : "v"(x));
  return r;
}

// XOR swizzle for 128-byte LDS rows (G4 / m214 pattern)
__device__ __forceinline__ int swz(int row, int colByte) {
  return row * 128 + (colByte ^ ((row & 7) << 4));
}

// ---------------------------------------------------------------------------
// Fused prologue: f32->f16 converts for q,k,v,4 weights + mask bit-pack.
__global__ __launch_bounds__(256) void pre_kernel(
    const float* __restrict__ q, const float* __restrict__ k, const float* __restrict__ v,
    const float* __restrict__ wq, const float* __restrict__ wk,
    const float* __restrict__ wv, const float* __restrict__ wo,
    const int* __restrict__ mask,
    half_t* Xq, half_t* Xk, half_t* Xv,
    half_t* Wq, half_t* Wk, half_t* Wv, half_t* Wo,
    unsigned int* mbits) {
  const int gid = blockIdx.x, tid = threadIdx.x;
  if (gid < 16384) {  // converts: 4,194,304 float4 total
    int i = gid * 256 + tid;
    const float* src; half_t* dst; int off;
    if (i < 3145728) {  // q,k,v: 1M float4 each
      int rgn = i >> 20; off = i & 1048575;
      src = rgn == 0 ? q : rgn == 1 ? k : v;
      dst = rgn == 0 ? Xq : rgn == 1 ? Xk : Xv;
    } else {            // weights: 256K float4 each
      int j = i - 3145728;
      int rgn = j >> 18; off = j & 262143;
      src = rgn == 0 ? wq : rgn == 1 ? wk : rgn == 2 ? wv : wo;
      dst = rgn == 0 ? Wq : rgn == 1 ? Wk : rgn == 2 ? Wv : Wo;
    }
    float4 vv = ((const float4*)src)[off];
    h4 o;
    o[0] = (half_t)vv.x; o[1] = (half_t)vv.y; o[2] = (half_t)vv.z; o[3] = (half_t)vv.w;
    ((h4*)dst)[off] = o;
  } else {  // mask pack: 4,194,304 ints
    int i = (gid - 16384) * 256 + tid;
    int mv = mask[i];
    unsigned long long bm = __ballot(mv != 0);
    int lane = tid & 63;
    if (lane == 0)       mbits[i >> 5] = (unsigned int)bm;
    else if (lane == 32) mbits[i >> 5] = (unsigned int)(bm >> 32);
  }
}

// ---------------------------------------------------------------------------
// NT GEMM, 128x128 tile, BK=64, [128][64] f16 LDS with XOR-swizzle
// (pre-swizzled global source -> linear gload_lds dest -> swizzled ds_read;
// fragment ds_read_b128 then activates all 32 banks = optimal). 16 K-steps,
// 2 barriers each. EPI=0: f16 out; z=0 -> Q [B,H,S,64] scaled (1/8)*log2e;
// z=1 -> K; z=2 -> V^T [B,H,64,S]. EPI=1: f32 out row-major [M][N].
template <int EPI>
__global__ __launch_bounds__(256) void gemm_kernel(
    const half_t* __restrict__ A0, const half_t* __restrict__ A1, const half_t* __restrict__ A2,
    const half_t* __restrict__ W0, const half_t* __restrict__ W1, const half_t* __restrict__ W2,
    const float* __restrict__ b0, const float* __restrict__ b1, const float* __restrict__ b2,
    void* o0, void* o1, void* o2) {
  const half_t* A; const half_t* W; const float* bias; void* out; float scale;
  if (blockIdx.z == 0)      { A = A0; W = W0; bias = b0; out = o0; scale = (EPI == 0) ? 0.125f * LOG2E : 1.0f; }
  else if (blockIdx.z == 1) { A = A1; W = W1; bias = b1; out = o1; scale = 1.0f; }
  else                      { A = A2; W = W2; bias = b2; out = o2; scale = 1.0f; }

  __shared__ half_t As[128 * 64];
  __shared__ half_t Bs[128 * 64];
  const int tid = threadIdx.x;
  const int w = tid >> 6, lane = tid & 63;
  const int wm = w >> 1, wn = w & 1;
  const int bm = blockIdx.x, bn = blockIdx.y;

  f32x4 acc[4][4] = {};

  // staging: round p covers rows p*32+w*8 .. +8; lane supplies 16B at
  // source col (lane&7)*16 XOR ((lane>>3)<<4) within the 128B k-segment.
  const int r8 = lane >> 3;
  const int scb2 = ((lane & 7) * 16) ^ (r8 << 4);
  const char* Ab = (const char*)A + (size_t)(bm * 128) * 2048;
  const char* Wb = (const char*)W + (size_t)(bn * 128) * 2048;
  char* AsB = (char*)As;
  char* BsB = (char*)Bs;

  // fragment-read constants
  const int rr = lane & 15;
  const int kgB = (lane >> 4) * 16;
  const int swzr = (rr & 7) << 4;

  for (int kb0 = 0; kb0 < 2048; kb0 += 128) {
    __syncthreads();
#pragma unroll
    for (int p = 0; p < 4; ++p) {
      const int row = p * 32 + w * 8 + r8;
      const size_t srow = (size_t)row * 2048 + kb0 + scb2;
      gload_lds16(Ab + srow, AsB + (p * 32 + w * 8) * 128);
      gload_lds16(Wb + srow, BsB + (p * 32 + w * 8) * 128);
    }
    __syncthreads();

#pragma unroll
    for (int h = 0; h < 2; ++h) {
      const int kcb = (kgB + h * 64) ^ swzr;
      h8 af[4], bf[4];
#pragma unroll
      for (int i = 0; i < 4; ++i) {
        af[i] = *(const h8*)(AsB + (wm * 64 + i * 16 + rr) * 128 + kcb);
        bf[i] = *(const h8*)(BsB + (wn * 64 + i * 16 + rr) * 128 + kcb);
      }
#pragma unroll
      for (int i = 0; i < 4; ++i)
#pragma unroll
        for (int j = 0; j < 4; ++j)
          acc[i][j] = __builtin_amdgcn_mfma_f32_16x16x32_f16(af[i], bf[j], acc[i][j], 0, 0, 0);
    }
  }

  const int r0 = bm * 128 + wm * 64;
  const int c0 = bn * 128 + wn * 64;
#pragma unroll
  for (int j = 0; j < 4; ++j) {
    int col = c0 + j * 16 + (lane & 15);
    float bc = bias[col];
#pragma unroll
    for (int i = 0; i < 4; ++i) {
#pragma unroll
      for (int jj = 0; jj < 4; ++jj) {
        int row = r0 + i * 16 + (lane >> 4) * 4 + jj;
        float val = acc[i][j][jj] + bc;
        if (EPI == 0) {
          int bb = row >> 11, s = row & (S_LEN - 1);
          int hh = col >> 6, dk = col & 63;
          if (blockIdx.z == 2) {  // V^T: [B,H,64,S]
            ((half_t*)out)[((size_t)((bb * NHEAD + hh) * HDK + dk)) * S_LEN + s] = (half_t)val;
          } else {
            ((half_t*)out)[(((size_t)(bb * NHEAD + hh)) * S_LEN + s) * HDK + dk] =
                (half_t)(val * scale);
          }
        } else {
          ((float*)out)[(size_t)row * DMODEL + col] = val;
        }
      }
    }
  }
}

// ---------------------------------------------------------------------------
// Flash attention v6 (unchanged from R5): 4-wave/256-thread blocks, grid 1024
// = (8 xcd)x(4 bh)x(32 q-tiles of 64). 2 q-groups x 2 k-halves per block;
// additive k-half merge (no running max; masked scores -> 0 so p=1.0 ==
// fp32 exp(1e-9)). K/V in 32 KB LDS double-buffer via global_load_lds.
__global__ __launch_bounds__(256, 4) void attn_kernel(
    const half_t* __restrict__ Qp, const half_t* __restrict__ Kp,
    const half_t* __restrict__ VTp, const unsigned int* __restrict__ mbits,
    half_t* __restrict__ AO) {
  __shared__ char smem[32768];  // K [2][8192] + V [2][8192]; merge area reuse

  const int tid = threadIdx.x, w = tid >> 6, lane = tid & 63;
  const int qg = w >> 1, kh = w & 1;
  const int id = blockIdx.x;
  const int xcd = id & 7, rest = id >> 3;
  const int bh = (xcd << 2) | (rest >> 5);
  const int qt = rest & 31;
  const int b = bh >> 4, h = bh & 15;
  const int q32 = lane & 31, hi = lane >> 5;
  const int qbase = qt * 64 + qg * 32;
  const half_t* Qb = Qp + (size_t)bh * (S_LEN * HDK);
  const char* Kb = (const char*)(Kp + (size_t)bh * (S_LEN * HDK));
  const char* VTb = (const char*)(VTp + (size_t)bh * (S_LEN * HDK));
  const unsigned int* mrow = mbits + (size_t)(qbase + q32) * (S_LEN / 32);

  char* Ks = smem;           // [2][8192]
  char* Vs = smem + 16384;   // [2][8192]
  const int srow = w * 16 + (lane >> 3);
  const int scb = (lane & 7) * 16;

  h8 qf[4];
#pragma unroll
  for (int s = 0; s < 4; ++s)
    qf[s] = *(const h8*)(Qb + (size_t)(qbase + q32) * HDK + s * 16 + hi * 8);

  f32x16 acc0 = {}, acc1 = {};
  float l_run = 0.f;

  unsigned int mw = mrow[kh];
#pragma unroll
  for (int p = 0; p < 2; ++p) {
    int r = srow + p * 8;
    gload_lds16(Kb + (size_t)r * 128 + (scb ^ ((r & 7) << 4)),
                Ks + (w * 16 + p * 8) * 128);
    gload_lds16(VTb + (size_t)r * (S_LEN * 2) + (scb ^ ((r & 7) << 4)),
                Vs + (w * 16 + p * 8) * 128);
  }
  __syncthreads();

  int cur = 0;
  for (int t = 0; t < 32; ++t) {
    const unsigned int mwc = mw >> (hi * 4);

    if (t < 31) {
      const int kvn = t + 1;
#pragma unroll
      for (int p = 0; p < 2; ++p) {
        int r = srow + p * 8;
        gload_lds16(Kb + (size_t)(kvn * 64 + r) * 128 + (scb ^ ((r & 7) << 4)),
                    Ks + (cur ^ 1) * 8192 + (w * 16 + p * 8) * 128);
        gload_lds16(VTb + (size_t)r * (S_LEN * 2) + kvn * 128 + (scb ^ ((r & 7) << 4)),
                    Vs + (cur ^ 1) * 8192 + (w * 16 + p * 8) * 128);
      }
      mw = mrow[kvn * 2 + kh];
    }

    const char* kb = Ks + cur * 8192;
    const char* vb = Vs + cur * 8192;
    f32x16 sc = {};
    __builtin_amdgcn_s_setprio(1);
#pragma unroll
    for (int s = 0; s < 4; ++s) {
      h8 kf = *(const h8*)(kb + swz(kh * 32 + q32, s * 32 + hi * 16));
      sc = __builtin_amdgcn_mfma_f32_32x32x16_f16(kf, qf[s], sc, 0, 0, 0);
    }
    __builtin_amdgcn_s_setprio(0);

    h8 vf00 = *(const h8*)(vb + swz(q32, kh * 64 + hi * 16));
    h8 vf01 = *(const h8*)(vb + swz(q32, kh * 64 + 32 + hi * 16));
    h8 vf10 = *(const h8*)(vb + swz(32 + q32, kh * 64 + hi * 16));
    h8 vf11 = *(const h8*)(vb + swz(32 + q32, kh * 64 + 32 + hi * 16));

#pragma unroll
    for (int rg = 0; rg < 16; ++rg) {
      const int bit = (rg & 3) + 8 * (rg >> 2);
      float p = fast_exp2(((mwc >> bit) & 1u) ? sc[rg] : 0.0f);
      sc[rg] = p;
      l_run += p;
    }

    h8 pb[2];
#pragma unroll
    for (int s = 0; s < 2; ++s) {
      const int rb = s * 8;
      union { h2 h; unsigned int u; } c01, c23, c45, c67;
      c01.h[0] = (half_t)sc[rb + 0]; c01.h[1] = (half_t)sc[rb + 1];
      c23.h[0] = (half_t)sc[rb + 2]; c23.h[1] = (half_t)sc[rb + 3];
      c45.h[0] = (half_t)sc[rb + 4]; c45.h[1] = (half_t)sc[rb + 5];
      c67.h[0] = (half_t)sc[rb + 6]; c67.h[1] = (half_t)sc[rb + 7];
      auto rA = __builtin_amdgcn_permlane32_swap(c01.u, c45.u, false, false);
      auto rB = __builtin_amdgcn_permlane32_swap(c23.u, c67.u, false, false);
      union { unsigned int u[4]; h8 v; } bw;
      bw.u[0] = rA[0]; bw.u[1] = rB[0]; bw.u[2] = rA[1]; bw.u[3] = rB[1];
      pb[s] = bw.v;
    }

    __builtin_amdgcn_s_setprio(1);
    acc0 = __builtin_amdgcn_mfma_f32_32x32x16_f16(vf00, pb[0], acc0, 0, 0, 0);
    acc1 = __builtin_amdgcn_mfma_f32_32x32x16_f16(vf10, pb[0], acc1, 0, 0, 0);
    acc0 = __builtin_amdgcn_mfma_f32_32x32x16_f16(vf01, pb[1], acc0, 0, 0, 0);
    acc1 = __builtin_amdgcn_mfma_f32_32x32x16_f16(vf11, pb[1], acc1, 0, 0, 0);
    __builtin_amdgcn_s_setprio(0);

    __syncthreads();
    cur ^= 1;
  }

  float* my = (float*)smem + (qg * 64 + lane) * 33;
  if (kh) {
#pragma unroll
    for (int rg = 0; rg < 16; ++rg) { my[rg] = acc0[rg]; my[16 + rg] = acc1[rg]; }
    my[32] = l_run;
  }
  __syncthreads();
  if (!kh) {
#pragma unroll
    for (int rg = 0; rg < 16; ++rg) { acc0[rg] += my[rg]; acc1[rg] += my[16 + rg]; }
    l_run += my[32];
    l_run += __shfl_xor(l_run, 32);

    const float inv = 1.0f / l_run;
    const int qrow = qbase + q32;
    half_t* aob = AO + (size_t)(b * S_LEN + qrow) * DMODEL + h * HDK;
#pragma unroll
    for (int rq = 0; rq < 4; ++rq) {
      h4 s0, s1;
#pragma unroll
      for (int j = 0; j < 4; ++j) {
        s0[j] = (half_t)(acc0[rq * 4 + j] * inv);
        s1[j] = (half_t)(acc1[rq * 4 + j] * inv);
      }
      const int d0 = 8 * rq + 4 * hi;
      *(h4*)(aob + d0) = s0;
      *(h4*)(aob + 32 + d0) = s1;
    }
  }
}

// ---------------------------------------------------------------------------
extern "C" void kernel_launch(void* const* d_in, const int* in_sizes, int n_in,
                              void* d_out, int out_size, void* d_ws, size_t ws_size,
                              hipStream_t stream) {
  const float* q    = (const float*)d_in[0];
  const float* k    = (const float*)d_in[1];
  const float* v    = (const float*)d_in[2];
  const int*   mask = (const int*)d_in[3];
  const float* wq_w = (const float*)d_in[4];
  const float* wq_b = (const float*)d_in[5];
  const float* wk_w = (const float*)d_in[6];
  const float* wk_b = (const float*)d_in[7];
  const float* wv_w = (const float*)d_in[8];
  const float* wv_b = (const float*)d_in[9];
  const float* wo_w = (const float*)d_in[10];
  const float* wo_b = (const float*)d_in[11];
  float* out = (float*)d_out;

  char* ws = (char*)d_ws;
  const size_t MB = (size_t)1 << 20;
  half_t* Xq = (half_t*)(ws + 0 * MB);
  half_t* Xk = (half_t*)(ws + 8 * MB);
  half_t* Xv = (half_t*)(ws + 16 * MB);
  half_t* Wq = (half_t*)(ws + 24 * MB);
  half_t* Wk = (half_t*)(ws + 26 * MB);
  half_t* Wv = (half_t*)(ws + 28 * MB);
  half_t* Wo = (half_t*)(ws + 30 * MB);
  half_t* Qp = (half_t*)(ws + 32 * MB);
  half_t* Kp = (half_t*)(ws + 40 * MB);
  half_t* VT = (half_t*)(ws + 48 * MB);
  unsigned int* mbits = (unsigned int*)(ws + 56 * MB);
  half_t* AO = Xq;  // Xq dead after projections

  pre_kernel<<<32768, 256, 0, stream>>>(q, k, v, wq_w, wk_w, wv_w, wo_w, mask,
                                        Xq, Xk, Xv, Wq, Wk, Wv, Wo, mbits);
  gemm_kernel<0><<<dim3(32, 8, 3), 256, 0, stream>>>(
      Xq, Xk, Xv, Wq, Wk, Wv, wq_b, wk_b, wv_b, (void*)Qp, (void*)Kp, (void*)VT);
  attn_kernel<<<1024, 256, 0, stream>>>(Qp, Kp, VT, mbits, AO);
  gemm_kernel<1><<<dim3(32, 8, 1), 256, 0, stream>>>(
      AO, AO, AO, Wo, Wo, Wo, wo_b, wo_b, wo_b, (void*)out, (void*)out, (void*)out);

  (void)in_sizes; (void)n_in; (void)out_size; (void)ws_size;
}

// Round 8
// 152.220 us; speedup vs baseline: 1.0294x; 1.0294x over previous
//
#include <hip/hip_runtime.h>

typedef _Float16 half_t;
typedef _Float16 h8 __attribute__((ext_vector_type(8)));
typedef _Float16 h4 __attribute__((ext_vector_type(4)));
typedef _Float16 h2 __attribute__((ext_vector_type(2)));
typedef float f32x4 __attribute__((ext_vector_type(4)));
typedef float f32x16 __attribute__((ext_vector_type(16)));

#define S_LEN 2048
#define DMODEL 1024
#define NHEAD 16
#define HDK 64
#define NB 2
#define MROWS (NB * S_LEN)  // 4096
#define LOG2E 1.44269504089f

// ---------------------------------------------------------------------------
__device__ __forceinline__ void gload_lds16(const void* g, void* l) {
  __builtin_amdgcn_global_load_lds(
      (const __attribute__((address_space(1))) unsigned int*)g,
      (__attribute__((address_space(3))) unsigned int*)l, 16, 0, 0);
}

// v_exp_f32 computes 2^x natively (scores carry log2e folded in from Q scale)
__device__ __forceinline__ float fast_exp2(float x) {
  float r;
  asm("v_exp_f32 %0, %1" : "=v"(r) : "v"(x));
  return r;
}

// XOR swizzle for 128-byte LDS rows (G4 / m214 pattern) — attn tiles
__device__ __forceinline__ int swz(int row, int colByte) {
  return row * 128 + (colByte ^ ((row & 7) << 4));
}

// ---------------------------------------------------------------------------
// Fused prologue: f32->f16 converts for q,k,v,4 weights + mask bit-pack.
__global__ __launch_bounds__(256) void pre_kernel(
    const float* __restrict__ q, const float* __restrict__ k, const float* __restrict__ v,
    const float* __restrict__ wq, const float* __restrict__ wk,
    const float* __restrict__ wv, const float* __restrict__ wo,
    const int* __restrict__ mask,
    half_t* Xq, half_t* Xk, half_t* Xv,
    half_t* Wq, half_t* Wk, half_t* Wv, half_t* Wo,
    unsigned int* mbits) {
  const int gid = blockIdx.x, tid = threadIdx.x;
  if (gid < 16384) {  // converts: 4,194,304 float4 total
    int i = gid * 256 + tid;
    const float* src; half_t* dst; int off;
    if (i < 3145728) {  // q,k,v: 1M float4 each
      int rgn = i >> 20; off = i & 1048575;
      src = rgn == 0 ? q : rgn == 1 ? k : v;
      dst = rgn == 0 ? Xq : rgn == 1 ? Xk : Xv;
    } else {            // weights: 256K float4 each
      int j = i - 3145728;
      int rgn = j >> 18; off = j & 262143;
      src = rgn == 0 ? wq : rgn == 1 ? wk : rgn == 2 ? wv : wo;
      dst = rgn == 0 ? Wq : rgn == 1 ? Wk : rgn == 2 ? Wv : Wo;
    }
    float4 vv = ((const float4*)src)[off];
    h4 o;
    o[0] = (half_t)vv.x; o[1] = (half_t)vv.y; o[2] = (half_t)vv.z; o[3] = (half_t)vv.w;
    ((h4*)dst)[off] = o;
  } else {  // mask pack: 4,194,304 ints
    int i = (gid - 16384) * 256 + tid;
    int mv = mask[i];
    unsigned long long bm = __ballot(mv != 0);
    int lane = tid & 63;
    if (lane == 0)       mbits[i >> 5] = (unsigned int)bm;
    else if (lane == 32) mbits[i >> 5] = (unsigned int)(bm >> 32);
  }
}

// ---------------------------------------------------------------------------
// NT GEMM: R2-proven m97/BK=32 layout + (1) LDS double-buffer with ONE
// barrier per K-step (stage t+1 -> compute t -> barrier), (2) both-sides
// XOR swizzle ^((row&3)<<4) on the 64B k-segment (pre-swizzled global
// source, linear gload_lds dest, swizzled ds_read -> all 32 banks),
// (3) XCD-chunked flat grid (bm-major; nwg%8==0 so the simple map is
// bijective). EPI=0: f16 out; z=0 Q*(1/8*log2e) [B,H,S,64]; z=1 K; z=2 V^T
// [B,H,64,S]. EPI=1: f32 out row-major [M][N].
template <int EPI>
__global__ __launch_bounds__(256) void gemm_kernel(
    const half_t* __restrict__ A0, const half_t* __restrict__ A1, const half_t* __restrict__ A2,
    const half_t* __restrict__ W0, const half_t* __restrict__ W1, const half_t* __restrict__ W2,
    const float* __restrict__ b0, const float* __restrict__ b1, const float* __restrict__ b2,
    void* o0, void* o1, void* o2) {
  // flat grid -> xcd-chunked nid -> (z, bm, bn); 256 blocks per z slice
  const int nwg = gridDim.x;
  const int cpx = nwg >> 3;
  const int id = blockIdx.x;
  const int nid = (id & 7) * cpx + (id >> 3);
  const int z = nid >> 8;
  const int rmn = nid & 255;
  const int bm = rmn >> 3, bn = rmn & 7;

  const half_t* A; const half_t* W; const float* bias; void* out; float scale;
  if (z == 0)      { A = A0; W = W0; bias = b0; out = o0; scale = (EPI == 0) ? 0.125f * LOG2E : 1.0f; }
  else if (z == 1) { A = A1; W = W1; bias = b1; out = o1; scale = 1.0f; }
  else             { A = A2; W = W2; bias = b2; out = o2; scale = 1.0f; }

  __shared__ half_t As[2][128 * 32];
  __shared__ half_t Bs[2][128 * 32];
  const int tid = threadIdx.x;
  const int w = tid >> 6, lane = tid & 63;
  const int wm = w >> 1, wn = w & 1;
  const int crow = lane >> 2;                              // 0..15
  const int ckb = ((lane & 3) * 16) ^ ((crow & 3) << 4);   // pre-swizzled src byte col

  f32x4 acc[4][4] = {};

  const char* Ar0 = (const char*)A + (size_t)(bm * 128 + w * 16 + crow) * 2048 + ckb;
  const char* Ar1 = Ar0 + 64 * 2048;
  const char* Wr0 = (const char*)W + (size_t)(bn * 128 + w * 16 + crow) * 2048 + ckb;
  const char* Wr1 = Wr0 + 64 * 2048;

  // fragment-read constants
  const int rr = lane & 15;
  const int kkB = (lane >> 4) * 16;            // byte offset of this group's 8 elems
  const int kswz = (rr & 3) << 4;

#define GSTAGE(buf, ktB)                                     \
  do {                                                       \
    gload_lds16(Ar0 + (ktB), As[buf] + w * 512);             \
    gload_lds16(Ar1 + (ktB), As[buf] + (w + 4) * 512);       \
    gload_lds16(Wr0 + (ktB), Bs[buf] + w * 512);             \
    gload_lds16(Wr1 + (ktB), Bs[buf] + (w + 4) * 512);       \
  } while (0)

  GSTAGE(0, 0);
  __syncthreads();

  int cur = 0;
  for (int ktB = 0; ktB < 2048; ktB += 64) {
    if (ktB + 64 < 2048) GSTAGE(cur ^ 1, ktB + 64);

    const char* AsB = (const char*)As[cur];
    const char* BsB = (const char*)Bs[cur];
    h8 af[4], bf[4];
#pragma unroll
    for (int i = 0; i < 4; ++i) {
      af[i] = *(const h8*)(AsB + (wm * 64 + i * 16 + rr) * 64 + (kkB ^ kswz));
      bf[i] = *(const h8*)(BsB + (wn * 64 + i * 16 + rr) * 64 + (kkB ^ kswz));
    }
#pragma unroll
    for (int i = 0; i < 4; ++i)
#pragma unroll
      for (int j = 0; j < 4; ++j)
        acc[i][j] = __builtin_amdgcn_mfma_f32_16x16x32_f16(af[i], bf[j], acc[i][j], 0, 0, 0);

    __syncthreads();  // stage(t+1) drained; all waves done reading buf cur
    cur ^= 1;
  }
#undef GSTAGE

  const int r0 = bm * 128 + wm * 64;
  const int c0 = bn * 128 + wn * 64;
#pragma unroll
  for (int j = 0; j < 4; ++j) {
    int col = c0 + j * 16 + (lane & 15);
    float bc = bias[col];
#pragma unroll
    for (int i = 0; i < 4; ++i) {
#pragma unroll
      for (int jj = 0; jj < 4; ++jj) {
        int row = r0 + i * 16 + (lane >> 4) * 4 + jj;
        float val = acc[i][j][jj] + bc;
        if (EPI == 0) {
          int bb = row >> 11, s = row & (S_LEN - 1);
          int hh = col >> 6, dk = col & 63;
          if (z == 2) {  // V^T: [B,H,64,S]
            ((half_t*)out)[((size_t)((bb * NHEAD + hh) * HDK + dk)) * S_LEN + s] = (half_t)val;
          } else {
            ((half_t*)out)[(((size_t)(bb * NHEAD + hh)) * S_LEN + s) * HDK + dk] =
                (half_t)(val * scale);
          }
        } else {
          ((float*)out)[(size_t)row * DMODEL + col] = val;
        }
      }
    }
  }
}

// ---------------------------------------------------------------------------
// Flash attention v6 (byte-identical to R5/R6): 4-wave/256-thread blocks,
// grid 1024 = (8 xcd)x(4 bh)x(32 q-tiles of 64). 2 q-groups x 2 k-halves per
// block; additive k-half merge (no running max; masked scores -> 0 so p=1.0
// == fp32 exp(1e-9)). K/V in 32 KB LDS double-buffer via global_load_lds.
__global__ __launch_bounds__(256, 4) void attn_kernel(
    const half_t* __restrict__ Qp, const half_t* __restrict__ Kp,
    const half_t* __restrict__ VTp, const unsigned int* __restrict__ mbits,
    half_t* __restrict__ AO) {
  __shared__ char smem[32768];  // K [2][8192] + V [2][8192]; merge area reuse

  const int tid = threadIdx.x, w = tid >> 6, lane = tid & 63;
  const int qg = w >> 1, kh = w & 1;
  const int id = blockIdx.x;
  const int xcd = id & 7, rest = id >> 3;
  const int bh = (xcd << 2) | (rest >> 5);
  const int qt = rest & 31;
  const int b = bh >> 4, h = bh & 15;
  const int q32 = lane & 31, hi = lane >> 5;
  const int qbase = qt * 64 + qg * 32;
  const half_t* Qb = Qp + (size_t)bh * (S_LEN * HDK);
  const char* Kb = (const char*)(Kp + (size_t)bh * (S_LEN * HDK));
  const char* VTb = (const char*)(VTp + (size_t)bh * (S_LEN * HDK));
  const unsigned int* mrow = mbits + (size_t)(qbase + q32) * (S_LEN / 32);

  char* Ks = smem;           // [2][8192]
  char* Vs = smem + 16384;   // [2][8192]
  const int srow = w * 16 + (lane >> 3);
  const int scb = (lane & 7) * 16;

  h8 qf[4];
#pragma unroll
  for (int s = 0; s < 4; ++s)
    qf[s] = *(const h8*)(Qb + (size_t)(qbase + q32) * HDK + s * 16 + hi * 8);

  f32x16 acc0 = {}, acc1 = {};
  float l_run = 0.f;

  unsigned int mw = mrow[kh];
#pragma unroll
  for (int p = 0; p < 2; ++p) {
    int r = srow + p * 8;
    gload_lds16(Kb + (size_t)r * 128 + (scb ^ ((r & 7) << 4)),
                Ks + (w * 16 + p * 8) * 128);
    gload_lds16(VTb + (size_t)r * (S_LEN * 2) + (scb ^ ((r & 7) << 4)),
                Vs + (w * 16 + p * 8) * 128);
  }
  __syncthreads();

  int cur = 0;
  for (int t = 0; t < 32; ++t) {
    const unsigned int mwc = mw >> (hi * 4);

    if (t < 31) {
      const int kvn = t + 1;
#pragma unroll
      for (int p = 0; p < 2; ++p) {
        int r = srow + p * 8;
        gload_lds16(Kb + (size_t)(kvn * 64 + r) * 128 + (scb ^ ((r & 7) << 4)),
                    Ks + (cur ^ 1) * 8192 + (w * 16 + p * 8) * 128);
        gload_lds16(VTb + (size_t)r * (S_LEN * 2) + kvn * 128 + (scb ^ ((r & 7) << 4)),
                    Vs + (cur ^ 1) * 8192 + (w * 16 + p * 8) * 128);
      }
      mw = mrow[kvn * 2 + kh];
    }

    const char* kb = Ks + cur * 8192;
    const char* vb = Vs + cur * 8192;
    f32x16 sc = {};
    __builtin_amdgcn_s_setprio(1);
#pragma unroll
    for (int s = 0; s < 4; ++s) {
      h8 kf = *(const h8*)(kb + swz(kh * 32 + q32, s * 32 + hi * 16));
      sc = __builtin_amdgcn_mfma_f32_32x32x16_f16(kf, qf[s], sc, 0, 0, 0);
    }
    __builtin_amdgcn_s_setprio(0);

    h8 vf00 = *(const h8*)(vb + swz(q32, kh * 64 + hi * 16));
    h8 vf01 = *(const h8*)(vb + swz(q32, kh * 64 + 32 + hi * 16));
    h8 vf10 = *(const h8*)(vb + swz(32 + q32, kh * 64 + hi * 16));
    h8 vf11 = *(const h8*)(vb + swz(32 + q32, kh * 64 + 32 + hi * 16));

#pragma unroll
    for (int rg = 0; rg < 16; ++rg) {
      const int bit = (rg & 3) + 8 * (rg >> 2);
      float p = fast_exp2(((mwc >> bit) & 1u) ? sc[rg] : 0.0f);
      sc[rg] = p;
      l_run += p;
    }

    h8 pb[2];
#pragma unroll
    for (int s = 0; s < 2; ++s) {
      const int rb = s * 8;
      union { h2 h; unsigned int u; } c01, c23, c45, c67;
      c01.h[0] = (half_t)sc[rb + 0]; c01.h[1] = (half_t)sc[rb + 1];
      c23.h[0] = (half_t)sc[rb + 2]; c23.h[1] = (half_t)sc[rb + 3];
      c45.h[0] = (half_t)sc[rb + 4]; c45.h[1] = (half_t)sc[rb + 5];
      c67.h[0] = (half_t)sc[rb + 6]; c67.h[1] = (half_t)sc[rb + 7];
      auto rA = __builtin_amdgcn_permlane32_swap(c01.u, c45.u, false, false);
      auto rB = __builtin_amdgcn_permlane32_swap(c23.u, c67.u, false, false);
      union { unsigned int u[4]; h8 v; } bw;
      bw.u[0] = rA[0]; bw.u[1] = rB[0]; bw.u[2] = rA[1]; bw.u[3] = rB[1];
      pb[s] = bw.v;
    }

    __builtin_amdgcn_s_setprio(1);
    acc0 = __builtin_amdgcn_mfma_f32_32x32x16_f16(vf00, pb[0], acc0, 0, 0, 0);
    acc1 = __builtin_amdgcn_mfma_f32_32x32x16_f16(vf10, pb[0], acc1, 0, 0, 0);
    acc0 = __builtin_amdgcn_mfma_f32_32x32x16_f16(vf01, pb[1], acc0, 0, 0, 0);
    acc1 = __builtin_amdgcn_mfma_f32_32x32x16_f16(vf11, pb[1], acc1, 0, 0, 0);
    __builtin_amdgcn_s_setprio(0);

    __syncthreads();
    cur ^= 1;
  }

  float* my = (float*)smem + (qg * 64 + lane) * 33;
  if (kh) {
#pragma unroll
    for (int rg = 0; rg < 16; ++rg) { my[rg] = acc0[rg]; my[16 + rg] = acc1[rg]; }
    my[32] = l_run;
  }
  __syncthreads();
  if (!kh) {
#pragma unroll
    for (int rg = 0; rg < 16; ++rg) { acc0[rg] += my[rg]; acc1[rg] += my[16 + rg]; }
    l_run += my[32];
    l_run += __shfl_xor(l_run, 32);

    const float inv = 1.0f / l_run;
    const int qrow = qbase + q32;
    half_t* aob = AO + (size_t)(b * S_LEN + qrow) * DMODEL + h * HDK;
#pragma unroll
    for (int rq = 0; rq < 4; ++rq) {
      h4 s0, s1;
#pragma unroll
      for (int j = 0; j < 4; ++j) {
        s0[j] = (half_t)(acc0[rq * 4 + j] * inv);
        s1[j] = (half_t)(acc1[rq * 4 + j] * inv);
      }
      const int d0 = 8 * rq + 4 * hi;
      *(h4*)(aob + d0) = s0;
      *(h4*)(aob + 32 + d0) = s1;
    }
  }
}

// ---------------------------------------------------------------------------
extern "C" void kernel_launch(void* const* d_in, const int* in_sizes, int n_in,
                              void* d_out, int out_size, void* d_ws, size_t ws_size,
                              hipStream_t stream) {
  const float* q    = (const float*)d_in[0];
  const float* k    = (const float*)d_in[1];
  const float* v    = (const float*)d_in[2];
  const int*   mask = (const int*)d_in[3];
  const float* wq_w = (const float*)d_in[4];
  const float* wq_b = (const float*)d_in[5];
  const float* wk_w = (const float*)d_in[6];
  const float* wk_b = (const float*)d_in[7];
  const float* wv_w = (const float*)d_in[8];
  const float* wv_b = (const float*)d_in[9];
  const float* wo_w = (const float*)d_in[10];
  const float* wo_b = (const float*)d_in[11];
  float* out = (float*)d_out;

  char* ws = (char*)d_ws;
  const size_t MB = (size_t)1 << 20;
  half_t* Xq = (half_t*)(ws + 0 * MB);
  half_t* Xk = (half_t*)(ws + 8 * MB);
  half_t* Xv = (half_t*)(ws + 16 * MB);
  half_t* Wq = (half_t*)(ws + 24 * MB);
  half_t* Wk = (half_t*)(ws + 26 * MB);
  half_t* Wv = (half_t*)(ws + 28 * MB);
  half_t* Wo = (half_t*)(ws + 30 * MB);
  half_t* Qp = (half_t*)(ws + 32 * MB);
  half_t* Kp = (half_t*)(ws + 40 * MB);
  half_t* VT = (half_t*)(ws + 48 * MB);
  unsigned int* mbits = (unsigned int*)(ws + 56 * MB);
  half_t* AO = Xq;  // Xq dead after projections

  pre_kernel<<<32768, 256, 0, stream>>>(q, k, v, wq_w, wk_w, wv_w, wo_w, mask,
                                        Xq, Xk, Xv, Wq, Wk, Wv, Wo, mbits);
  gemm_kernel<0><<<768, 256, 0, stream>>>(
      Xq, Xk, Xv, Wq, Wk, Wv, wq_b, wk_b, wv_b, (void*)Qp, (void*)Kp, (void*)VT);
  attn_kernel<<<1024, 256, 0, stream>>>(Qp, Kp, VT, mbits, AO);
  gemm_kernel<1><<<256, 256, 0, stream>>>(
      AO, AO, AO, Wo, Wo, Wo, wo_b, wo_b, wo_b, (void*)out, (void*)out, (void*)out);

  (void)in_sizes; (void)n_in; (void)out_size; (void)ws_size;
}